// Round 3
// baseline (1419.199 us; speedup 1.0000x reference)
//
#include <hip/hip_runtime.h>

// ---------------------------------------------------------------------------
// TransformerEncoderLayer on MI355X (gfx950).  B=4 L=2048 D=256 H=8 FF=128.
// Input dtype (fp32 vs bf16) detected at runtime from seq bit patterns;
// all compute in bf16 MFMA (v_mfma_f32_16x16x32_bf16) with fp32 accumulate.
// Layouts: A[m=lane&15][k=8*(lane>>4)+j], B[k=8*(lane>>4)+j][n=lane&15],
//          C/D[row=(lane>>4)*4+r][col=lane&15]
// ---------------------------------------------------------------------------

typedef unsigned short u16;
typedef unsigned int   u32;
typedef __bf16 bf16x8 __attribute__((ext_vector_type(8)));
typedef float  f32x4  __attribute__((ext_vector_type(4)));

#define MFMA(a, b, c) __builtin_amdgcn_mfma_f32_16x16x32_bf16(a, b, c, 0, 0, 0)

__device__ __forceinline__ float b2f(u16 h) {
  return __uint_as_float(((u32)h) << 16);
}
__device__ __forceinline__ u16 f2b(float f) {
  u32 u = __float_as_uint(f);
  u += 0x7FFFu + ((u >> 16) & 1u);   // round-to-nearest-even
  return (u16)(u >> 16);
}
__device__ __forceinline__ bf16x8 ldb8(const u16* p) { return *(const bf16x8*)p; }

// Detect fp32 vs bf16 from seq: bits 14:7 of a u32 are a bf16 exponent
// (~[114,130]) if the buffer is bf16, ~uniform if fp32 mantissa bits.
__device__ __forceinline__ int detect_f32(const void* seq) {
  const u32* s = (const u32*)seq;
  int cnt = 0;
  #pragma unroll
  for (int i = 0; i < 64; i++) {
    u32 e = (s[i] >> 7) & 0xFFu;
    cnt += (e >= 100u && e <= 140u) ? 1 : 0;
  }
  return cnt < 48;  // 1 => fp32
}

__device__ __forceinline__ u16 ldw(const void* W, size_t idx, int isf32) {
  return isf32 ? f2b(((const float*)W)[idx]) : ((const u16*)W)[idx];
}

// ---------------------------------------------------------------------------
// Ingest: canonicalize seq (2M elems) + 6 small vectors to bf16 in ws.
// grid 2054 x 256: blocks 0..2047 -> seq (4 elems/thread), 2048+t -> vector t.
// vecs slots (256 u16 each): g1, be1, b1(128), b2, g2, be2.
// ---------------------------------------------------------------------------
__global__ __launch_bounds__(256) void ingest_kernel(
    const void* __restrict__ seq, const void* __restrict__ g1,
    const void* __restrict__ be1, const void* __restrict__ b1,
    const void* __restrict__ b2v, const void* __restrict__ g2,
    const void* __restrict__ be2, u16* __restrict__ sbuf,
    u16* __restrict__ vecs) {
  int isf32 = detect_f32(seq);
  int bx = blockIdx.x, tid = threadIdx.x;
  if (bx < 2048) {
    size_t i = (size_t)bx * 1024 + tid * 4;
    if (isf32) {
      const float* sp = (const float*)seq;
      u16 o0 = f2b(sp[i]), o1 = f2b(sp[i + 1]), o2 = f2b(sp[i + 2]), o3 = f2b(sp[i + 3]);
      uint2 ov; ov.x = (u32)o0 | ((u32)o1 << 16); ov.y = (u32)o2 | ((u32)o3 << 16);
      *(uint2*)(sbuf + i) = ov;
    } else {
      *(uint2*)(sbuf + i) = ((const uint2*)seq)[i >> 2];
    }
  } else {
    int t = bx - 2048;
    const void* src; int n;
    switch (t) {
      case 0: src = g1;  n = 256; break;
      case 1: src = be1; n = 256; break;
      case 2: src = b1;  n = 128; break;
      case 3: src = b2v; n = 256; break;
      case 4: src = g2;  n = 256; break;
      default: src = be2; n = 256; break;
    }
    if (tid < n) vecs[t * 256 + tid] = ldw(src, tid, isf32);
  }
}

// ---------------------------------------------------------------------------
// Pack weights into B-fragment-linear layout: frag f=(kt*NT+nt),
// elements (f*64+lane)*8+j ; j = consecutive k.  grid (256, 6), 256 thr.
// ---------------------------------------------------------------------------
__global__ __launch_bounds__(256) void pack_kernel(
    const void* __restrict__ Wq, const void* __restrict__ Wk,
    const void* __restrict__ Wv, const void* __restrict__ Wo,
    const void* __restrict__ W1, const void* __restrict__ W2,
    const void* __restrict__ seq,
    u16* __restrict__ pWq, u16* __restrict__ pWk, u16* __restrict__ pWv,
    u16* __restrict__ pWo, u16* __restrict__ pW1, u16* __restrict__ pW2) {
  int isf32 = detect_f32(seq);
  const void* W; u16* P; int K, N;
  switch (blockIdx.y) {
    case 0: W = Wq; P = pWq; K = 256;  N = 2048; break;
    case 1: W = Wk; P = pWk; K = 256;  N = 2048; break;
    case 2: W = Wv; P = pWv; K = 256;  N = 2048; break;
    case 3: W = Wo; P = pWo; K = 2048; N = 256;  break;
    case 4: W = W1; P = pW1; K = 256;  N = 128;  break;
    default: W = W2; P = pW2; K = 128; N = 256;  break;
  }
  int t = blockIdx.x * 256 + threadIdx.x;
  int total = (K >> 5) * (N >> 4) * 64;
  if (t >= total) return;
  int lane = t & 63, f = t >> 6;
  int NT = N >> 4;
  int kt = f / NT, nt = f - kt * NT;
  int row0 = kt * 32 + ((lane >> 4) << 3);
  int col = nt * 16 + (lane & 15);
  u16 e[8];
  #pragma unroll
  for (int j = 0; j < 8; j++) e[j] = ldw(W, (size_t)(row0 + j) * N + col, isf32);
  uint4 u;
  u.x = (u32)e[0] | ((u32)e[1] << 16);
  u.y = (u32)e[2] | ((u32)e[3] << 16);
  u.z = (u32)e[4] | ((u32)e[5] << 16);
  u.w = (u32)e[6] | ((u32)e[7] << 16);
  *(uint4*)(P + ((size_t)f * 64 + lane) * 8) = u;
}

// ---------------------------------------------------------------------------
// QKV projection for one h-chunk: X(8192x256) @ W(256, hc*256) -> [B,hc,L,D].
// grid (2*hc, 64, 3), 256 threads (4 waves x 32 rows each).
// ---------------------------------------------------------------------------
__global__ __launch_bounds__(256) void qkv_kernel(
    const u16* __restrict__ X,
    const u16* __restrict__ pWq, const u16* __restrict__ pWk,
    const u16* __restrict__ pWv,
    u16* __restrict__ Qo, u16* __restrict__ Ko, u16* __restrict__ Vo,
    int ntbase, int hc) {
  __shared__ u16 blds[64 * 512];  // 8 kt x 8 nt frags = 64 KB
  const u16* Pw = (blockIdx.z == 0) ? pWq : ((blockIdx.z == 1) ? pWk : pWv);
  u16* Out = (blockIdx.z == 0) ? Qo : ((blockIdx.z == 1) ? Ko : Vo);
  int tid = threadIdx.x, lane = tid & 63, w = tid >> 6;
  int nt0 = ntbase + blockIdx.x * 8;   // global n-tile base for this block
  #pragma unroll
  for (int i = 0; i < 16; i++) {
    int u = tid + i * 256;          // 0..4095 uint4s
    int fl = u >> 6, q = u & 63;
    int kt = fl >> 3, nt = fl & 7;
    ((uint4*)blds)[u] = ((const uint4*)Pw)[(size_t)(kt * 128 + nt0 + nt) * 64 + q];
  }
  __syncthreads();
  int m0 = blockIdx.y * 128 + w * 32;
  f32x4 acc[2][8] = {};
  for (int kt = 0; kt < 8; kt++) {
    bf16x8 a0 = ldb8(X + (size_t)(m0 + (lane & 15)) * 256 + kt * 32 + (lane >> 4) * 8);
    bf16x8 a1 = ldb8(X + (size_t)(m0 + 16 + (lane & 15)) * 256 + kt * 32 + (lane >> 4) * 8);
    const u16* bp = blds + (size_t)kt * 8 * 512 + (size_t)lane * 8;
    #pragma unroll
    for (int nt = 0; nt < 8; nt++) {
      bf16x8 b = ldb8(bp + nt * 512);
      acc[0][nt] = MFMA(a0, b, acc[0][nt]);
      acc[1][nt] = MFMA(a1, b, acc[1][nt]);
    }
  }
  #pragma unroll
  for (int mt = 0; mt < 2; mt++) {
    int rbase = m0 + mt * 16 + (lane >> 4) * 4;
    #pragma unroll
    for (int nt = 0; nt < 8; nt++) {
      int nl = blockIdx.x * 128 + nt * 16 + (lane & 15);  // within chunk
      int hl = nl >> 8, dd = nl & 255;
      #pragma unroll
      for (int r = 0; r < 4; r++) {
        int m = rbase + r;
        int bi = m >> 11, l = m & 2047;
        Out[((size_t)(bi * hc + hl) * 2048 + l) * 256 + dd] = f2b(acc[mt][nt][r]);
      }
    }
  }
}

// ---------------------------------------------------------------------------
// Flash attention per (b,hl).  grid (4*hc, 32), 256 threads.
// 64 queries/block (16/wave), 32-key steps. scale = 1/sqrt(256) = 1/16.
// ---------------------------------------------------------------------------
__global__ __launch_bounds__(256, 2) void attn_kernel(
    const u16* __restrict__ Q, const u16* __restrict__ K,
    const u16* __restrict__ V, u16* __restrict__ O) {
  __shared__ u16 klds[32 * 264];        // K-tile [key][d], stride 264
  __shared__ u16 vlds[256 * 40];        // V-tile transposed [d][key], stride 40
  __shared__ u16 plds[4 * 16 * 40];     // per-wave P [q][key], stride 40
  int tid = threadIdx.x, lane = tid & 63, w = tid >> 6;
  int bh = blockIdx.x, qt = blockIdx.y;
  const u16* Qb = Q + (size_t)bh * 2048 * 256;
  const u16* Kb = K + (size_t)bh * 2048 * 256;
  const u16* Vb = V + (size_t)bh * 2048 * 256;
  u16* Ob = O + (size_t)bh * 2048 * 256;
  int q0 = qt * 64 + w * 16;
  bf16x8 qf[8];
  #pragma unroll
  for (int kt = 0; kt < 8; kt++)
    qf[kt] = ldb8(Qb + (size_t)(q0 + (lane & 15)) * 256 + kt * 32 + (lane >> 4) * 8);
  f32x4 o[16] = {};
  float m_i[4] = {-1e30f, -1e30f, -1e30f, -1e30f};
  float l_i[4] = {0.f, 0.f, 0.f, 0.f};
  const float cexp = 0.0625f * 1.44269504088896f;  // scale * log2(e)
  u16* pl = plds + w * 16 * 40;

  for (int s0 = 0; s0 < 2048; s0 += 32) {
    __syncthreads();  // previous iteration's LDS reads done before overwrite
    #pragma unroll
    for (int rep = 0; rep < 4; rep++) {
      int c = rep * 256 + tid;        // 0..1023 16B-chunks
      int row = c >> 5;               // 0..31 (key)
      int col = (c & 31) * 8;         // 0..248 (d)
      *(uint4*)(klds + row * 264 + col) =
          *(const uint4*)(Kb + (size_t)(s0 + row) * 256 + col);
      union { uint4 q; u16 s[8]; } vv;
      vv.q = *(const uint4*)(Vb + (size_t)(s0 + row) * 256 + col);
      #pragma unroll
      for (int j = 0; j < 8; j++) vlds[(col + j) * 40 + row] = vv.s[j];
    }
    __syncthreads();
    // S = Q K^T  (16 queries x 32 keys), fp32
    f32x4 s[2] = {};
    #pragma unroll
    for (int ntk = 0; ntk < 2; ntk++) {
      const u16* kp = klds + ((lane & 15) + 16 * ntk) * 264 + (lane >> 4) * 8;
      #pragma unroll
      for (int kt = 0; kt < 8; kt++) {
        bf16x8 b = ldb8(kp + kt * 32);
        s[ntk] = MFMA(qf[kt], b, s[ntk]);
      }
    }
    // online softmax (exp2 domain)
    float alpha[4];
    f32x4 p[2];
    #pragma unroll
    for (int r = 0; r < 4; r++) {
      float mx = fmaxf(s[0][r], s[1][r]);
      mx = fmaxf(mx, __shfl_xor(mx, 1));
      mx = fmaxf(mx, __shfl_xor(mx, 2));
      mx = fmaxf(mx, __shfl_xor(mx, 4));
      mx = fmaxf(mx, __shfl_xor(mx, 8));
      float mn = fmaxf(m_i[r], mx);
      alpha[r] = exp2f((m_i[r] - mn) * cexp);
      p[0][r] = exp2f((s[0][r] - mn) * cexp);
      p[1][r] = exp2f((s[1][r] - mn) * cexp);
      float ps = p[0][r] + p[1][r];
      ps += __shfl_xor(ps, 1);
      ps += __shfl_xor(ps, 2);
      ps += __shfl_xor(ps, 4);
      ps += __shfl_xor(ps, 8);
      l_i[r] = l_i[r] * alpha[r] + ps;
      m_i[r] = mn;
    }
    int need = (alpha[0] < 1.f) | (alpha[1] < 1.f) | (alpha[2] < 1.f) | (alpha[3] < 1.f);
    if (__any(need)) {
      #pragma unroll
      for (int nt = 0; nt < 16; nt++)
        #pragma unroll
        for (int r = 0; r < 4; r++) o[nt][r] *= alpha[r];
    }
    // P (C-layout) -> LDS -> A-layout
    #pragma unroll
    for (int ntk = 0; ntk < 2; ntk++)
      #pragma unroll
      for (int r = 0; r < 4; r++)
        pl[((lane >> 4) * 4 + r) * 40 + ntk * 16 + (lane & 15)] = f2b(p[ntk][r]);
    __syncthreads();
    bf16x8 pa = ldb8(pl + (lane & 15) * 40 + (lane >> 4) * 8);
    #pragma unroll
    for (int nt = 0; nt < 16; nt++) {
      bf16x8 vb = ldb8(vlds + ((lane & 15) + 16 * nt) * 40 + (lane >> 4) * 8);
      o[nt] = MFMA(pa, vb, o[nt]);
    }
  }
  float linv[4];
  #pragma unroll
  for (int r = 0; r < 4; r++) linv[r] = 1.0f / l_i[r];
  #pragma unroll
  for (int nt = 0; nt < 16; nt++) {
    int d = nt * 16 + (lane & 15);
    #pragma unroll
    for (int r = 0; r < 4; r++) {
      int qrow = q0 + (lane >> 4) * 4 + r;
      Ob[(size_t)qrow * 256 + d] = f2b(o[nt][r] * linv[r]);
    }
  }
}

// ---------------------------------------------------------------------------
// att_out(f32) += O_chunk @ Wo_chunk.  grid (128), 256 threads.
// ---------------------------------------------------------------------------
__global__ __launch_bounds__(256) void accum_kernel(
    const u16* __restrict__ Oc, const u16* __restrict__ pWo,
    float* __restrict__ att_out, int kt0, int hc) {
  __shared__ u16 blds[64 * 512];  // 4 kt x 16 nt frags = 64 KB
  int tid = threadIdx.x, lane = tid & 63, w = tid >> 6;
  int m0 = blockIdx.x * 64 + w * 16;
  int arow = m0 + (lane & 15);
  int bq = arow >> 11, lrow = arow & 2047;
  int ktn = hc * 8;
  f32x4 acc[16] = {};
  for (int k0 = 0; k0 < ktn; k0 += 4) {
    __syncthreads();
    #pragma unroll
    for (int i = 0; i < 16; i++) {
      int u = tid + i * 256;
      int fl = u >> 6, q = u & 63;
      int ktg = kt0 + k0 + (fl >> 4), nt = fl & 15;
      ((uint4*)blds)[u] = ((const uint4*)pWo)[(size_t)(ktg * 16 + nt) * 64 + q];
    }
    __syncthreads();
    #pragma unroll
    for (int kl = 0; kl < 4; kl++) {
      int ktl = k0 + kl;                 // local kt within chunk
      int hl = ktl >> 3;
      int d0 = (ktl & 7) * 32 + (lane >> 4) * 8;
      bf16x8 a = ldb8(Oc + ((size_t)(bq * hc + hl) * 2048 + lrow) * 256 + d0);
      const u16* bp = blds + (size_t)kl * 16 * 512 + (size_t)lane * 8;
      #pragma unroll
      for (int nt = 0; nt < 16; nt++) {
        bf16x8 b = ldb8(bp + nt * 512);
        acc[nt] = MFMA(a, b, acc[nt]);
      }
    }
  }
  int rbase = m0 + (lane >> 4) * 4;
  #pragma unroll
  for (int nt = 0; nt < 16; nt++) {
    int d = nt * 16 + (lane & 15);
    #pragma unroll
    for (int r = 0; r < 4; r++)
      att_out[(size_t)(rbase + r) * 256 + d] += acc[nt][r];
  }
}

// ---------------------------------------------------------------------------
// x = LN1(seq + att_out).  grid (2048), 256 threads; 1 wave per row.
// ---------------------------------------------------------------------------
__global__ __launch_bounds__(256) void ln1_kernel(
    const float* __restrict__ att_out, const u16* __restrict__ sbuf,
    const u16* __restrict__ vecs, u16* __restrict__ xout) {
  int tid = threadIdx.x, lane = tid & 63, w = tid >> 6;
  int row = blockIdx.x * 4 + w;
  const float* ar = att_out + (size_t)row * 256;
  f32x4 a = *(const f32x4*)(ar + lane * 4);
  uint2 sv = *(const uint2*)(sbuf + (size_t)row * 256 + lane * 4);
  float y[4];
  y[0] = a[0] + b2f((u16)(sv.x & 0xFFFF));
  y[1] = a[1] + b2f((u16)(sv.x >> 16));
  y[2] = a[2] + b2f((u16)(sv.y & 0xFFFF));
  y[3] = a[3] + b2f((u16)(sv.y >> 16));
  float sm = y[0] + y[1] + y[2] + y[3];
  sm += __shfl_xor(sm, 1);  sm += __shfl_xor(sm, 2);  sm += __shfl_xor(sm, 4);
  sm += __shfl_xor(sm, 8);  sm += __shfl_xor(sm, 16); sm += __shfl_xor(sm, 32);
  float mu = sm * (1.0f / 256.0f);
  float v = 0.f;
  #pragma unroll
  for (int j = 0; j < 4; j++) { float d = y[j] - mu; v += d * d; }
  v += __shfl_xor(v, 1);  v += __shfl_xor(v, 2);  v += __shfl_xor(v, 4);
  v += __shfl_xor(v, 8);  v += __shfl_xor(v, 16); v += __shfl_xor(v, 32);
  float rs = rsqrtf(v * (1.0f / 256.0f) + 1e-5f);
  u16 o[4];
  #pragma unroll
  for (int j = 0; j < 4; j++) {
    int d = lane * 4 + j;
    o[j] = f2b((y[j] - mu) * rs * b2f(vecs[d]) + b2f(vecs[256 + d]));
  }
  uint2 ov; ov.x = (u32)o[0] | ((u32)o[1] << 16); ov.y = (u32)o[2] | ((u32)o[3] << 16);
  *(uint2*)(xout + (size_t)row * 256 + lane * 4) = ov;
}

// ---------------------------------------------------------------------------
// FFN + LN2.  out = LN2(x + relu(x@W1+b1)@W2 + b2).  grid(128), 256 thr.
// Output dtype chosen at runtime (detected from seq).
// ---------------------------------------------------------------------------
__global__ __launch_bounds__(256) void ffn_ln2_kernel(
    const u16* __restrict__ x, const u16* __restrict__ pW1,
    const u16* __restrict__ pW2, const u16* __restrict__ vecs,
    const void* __restrict__ seq, void* __restrict__ out) {
  __shared__ u16 hbuf[4 * 16 * 136];  // per-wave h [16][128], stride 136
  int isf32 = detect_f32(seq);
  int tid = threadIdx.x, lane = tid & 63, w = tid >> 6;
  int m0 = blockIdx.x * 64 + w * 16;
  int arow = m0 + (lane & 15);
  u16* hb = hbuf + w * 16 * 136;
  // phase 1: h = relu(x @ W1 + b1)
  f32x4 acc1[8] = {};
  #pragma unroll
  for (int kt = 0; kt < 8; kt++) {
    bf16x8 a = ldb8(x + (size_t)arow * 256 + kt * 32 + (lane >> 4) * 8);
    const u16* bp = pW1 + ((size_t)kt * 8 * 64 + lane) * 8;
    #pragma unroll
    for (int nt = 0; nt < 8; nt++) {
      bf16x8 b = ldb8(bp + nt * 512);
      acc1[nt] = MFMA(a, b, acc1[nt]);
    }
  }
  #pragma unroll
  for (int nt = 0; nt < 8; nt++) {
    int col = nt * 16 + (lane & 15);
    float bb = b2f(vecs[512 + col]);
    #pragma unroll
    for (int r = 0; r < 4; r++) {
      float h = fmaxf(acc1[nt][r] + bb, 0.f);
      hb[((lane >> 4) * 4 + r) * 136 + col] = f2b(h);
    }
  }
  __syncthreads();
  // phase 2: y = h @ W2
  f32x4 acc2[16] = {};
  #pragma unroll
  for (int ks = 0; ks < 4; ks++) {
    bf16x8 a = ldb8(hb + (lane & 15) * 136 + ks * 32 + (lane >> 4) * 8);
    const u16* bp = pW2 + ((size_t)ks * 16 * 64 + lane) * 8;
    #pragma unroll
    for (int nt = 0; nt < 16; nt++) {
      bf16x8 b = ldb8(bp + nt * 512);
      acc2[nt] = MFMA(a, b, acc2[nt]);
    }
  }
  int rbase = m0 + (lane >> 4) * 4;
  #pragma unroll
  for (int nt = 0; nt < 16; nt++) {
    int d = nt * 16 + (lane & 15);
    float bb = b2f(vecs[768 + d]);
    #pragma unroll
    for (int r = 0; r < 4; r++)
      acc2[nt][r] += bb + b2f(x[(size_t)(rbase + r) * 256 + d]);
  }
  float mu[4], rs[4];
  #pragma unroll
  for (int r = 0; r < 4; r++) {
    float sm = 0.f;
    #pragma unroll
    for (int nt = 0; nt < 16; nt++) sm += acc2[nt][r];
    sm += __shfl_xor(sm, 1); sm += __shfl_xor(sm, 2);
    sm += __shfl_xor(sm, 4); sm += __shfl_xor(sm, 8);
    mu[r] = sm * (1.0f / 256.0f);
    float v = 0.f;
    #pragma unroll
    for (int nt = 0; nt < 16; nt++) { float dd = acc2[nt][r] - mu[r]; v += dd * dd; }
    v += __shfl_xor(v, 1); v += __shfl_xor(v, 2);
    v += __shfl_xor(v, 4); v += __shfl_xor(v, 8);
    rs[r] = rsqrtf(v * (1.0f / 256.0f) + 1e-5f);
  }
  #pragma unroll
  for (int nt = 0; nt < 16; nt++) {
    int d = nt * 16 + (lane & 15);
    float gg = b2f(vecs[1024 + d]), bb = b2f(vecs[1280 + d]);
    #pragma unroll
    for (int r = 0; r < 4; r++) {
      float val = (acc2[nt][r] - mu[r]) * rs[r] * gg + bb;
      size_t idx = (size_t)(rbase + r) * 256 + d;
      if (isf32) ((float*)out)[idx] = val;
      else       ((u16*)out)[idx]   = f2b(val);
    }
  }
}

// ---------------------------------------------------------------------------
// Sentinel: workspace too small — write 777.0 beacon.
// ---------------------------------------------------------------------------
__global__ __launch_bounds__(256) void sentinel_kernel(void* out, int n,
                                                       const void* seq) {
  int isf32 = detect_f32(seq);
  int i = blockIdx.x * 256 + threadIdx.x;
  if (i < n) {
    if (isf32) ((float*)out)[i] = 777.0f;
    else       ((u16*)out)[i]   = 0x4442;  // bf16(777.0)
  }
}

// ---------------------------------------------------------------------------
extern "C" void kernel_launch(void* const* d_in, const int* in_sizes, int n_in,
                              void* d_out, int out_size, void* d_ws, size_t ws_size,
                              hipStream_t stream) {
  (void)in_sizes; (void)n_in;
  const void* seq  = d_in[0];
  const void* Wq   = d_in[1];
  const void* Wk   = d_in[2];
  const void* Wv   = d_in[3];
  const void* Wo   = d_in[4];
  const void* g1   = d_in[5];
  const void* be1  = d_in[6];
  const void* W1   = d_in[7];
  const void* b1   = d_in[8];
  const void* W2   = d_in[9];
  const void* b2   = d_in[10];
  const void* g2   = d_in[11];
  const void* be2  = d_in[12];

  // ws layout (u16 element offsets)
  size_t o = 0;
  u16* ws = (u16*)d_ws;
  u16* pWq = ws + o; o += 524288;
  u16* pWk = ws + o; o += 524288;
  u16* pWv = ws + o; o += 524288;
  u16* pWo = ws + o; o += 524288;
  u16* pW1 = ws + o; o += 32768;
  u16* pW2 = ws + o; o += 32768;
  float* att = (float*)(ws + o); o += 4194304;   // 2M f32
  u16* xb   = ws + o; o += 2097152;
  u16* sbuf = ws + o; o += 2097152;
  u16* vecs = ws + o; o += 2048;
  size_t fixed_elems = o;

  // pick hc: largest in {8,4,2,1} s.t. fixed + 4*hc*2097152 elems fit
  int hc = 0;
  for (int c = 8; c >= 1; c >>= 1) {
    size_t need = (fixed_elems + (size_t)4 * c * 2097152) * 2;
    if (need <= ws_size) { hc = c; break; }
  }
  if (hc == 0) {
    sentinel_kernel<<<dim3((out_size + 255) / 256), 256, 0, stream>>>(
        d_out, out_size, seq);
    return;
  }
  u16* Qc = ws + o; o += (size_t)hc * 2097152;
  u16* Kc = ws + o; o += (size_t)hc * 2097152;
  u16* Vc = ws + o; o += (size_t)hc * 2097152;
  u16* Oc = ws + o;

  hipMemsetAsync(att, 0, 2097152 * sizeof(float), stream);
  ingest_kernel<<<dim3(2054), 256, 0, stream>>>(seq, g1, be1, b1, b2, g2, be2,
                                                sbuf, vecs);
  pack_kernel<<<dim3(256, 6), 256, 0, stream>>>(Wq, Wk, Wv, Wo, W1, W2, seq,
                                                pWq, pWk, pWv, pWo, pW1, pW2);
  int nchunks = 8 / hc;
  for (int c = 0; c < nchunks; c++) {
    qkv_kernel<<<dim3(2 * hc, 64, 3), 256, 0, stream>>>(
        sbuf, pWq, pWk, pWv, Qc, Kc, Vc, c * hc * 16, hc);
    attn_kernel<<<dim3(4 * hc, 32), 256, 0, stream>>>(Qc, Kc, Vc, Oc);
    accum_kernel<<<dim3(128), 256, 0, stream>>>(Oc, pWo, att, c * hc * 8, hc);
  }
  ln1_kernel<<<dim3(2048), 256, 0, stream>>>(att, sbuf, vecs, xb);
  ffn_ln2_kernel<<<dim3(128), 256, 0, stream>>>(xb, pW1, pW2, vecs, seq,
                                                (void*)d_out);
}

// Round 4
// 1026.657 us; speedup vs baseline: 1.3823x; 1.3823x over previous
//
#include <hip/hip_runtime.h>

// ---------------------------------------------------------------------------
// TransformerEncoderLayer on MI355X (gfx950).  B=4 L=2048 D=256 H=8 FF=128.
// Input dtype (fp32 vs bf16) detected at runtime from seq bit patterns;
// all compute in bf16 MFMA (v_mfma_f32_16x16x32_bf16) with fp32 accumulate.
// Layouts: A[m=lane&15][k=8*(lane>>4)+j], B[k=8*(lane>>4)+j][n=lane&15],
//          C/D[row=(lane>>4)*4+r][col=lane&15]
// R3: qkv stores V^T [B,h,D,L] so attention needs no in-loop LDS transpose
//     (removes the 32-way-conflict scalar scatter that was 70% of attn time).
// ---------------------------------------------------------------------------

typedef unsigned short u16;
typedef unsigned int   u32;
typedef __bf16 bf16x8 __attribute__((ext_vector_type(8)));
typedef float  f32x4  __attribute__((ext_vector_type(4)));

#define MFMA(a, b, c) __builtin_amdgcn_mfma_f32_16x16x32_bf16(a, b, c, 0, 0, 0)

__device__ __forceinline__ float b2f(u16 h) {
  return __uint_as_float(((u32)h) << 16);
}
__device__ __forceinline__ u16 f2b(float f) {
  u32 u = __float_as_uint(f);
  u += 0x7FFFu + ((u >> 16) & 1u);   // round-to-nearest-even
  return (u16)(u >> 16);
}
__device__ __forceinline__ bf16x8 ldb8(const u16* p) { return *(const bf16x8*)p; }

// Detect fp32 vs bf16 from seq: bits 14:7 of a u32 are a bf16 exponent
// (~[114,130]) if the buffer is bf16, ~uniform if fp32 mantissa bits.
__device__ __forceinline__ int detect_f32(const void* seq) {
  const u32* s = (const u32*)seq;
  int cnt = 0;
  #pragma unroll
  for (int i = 0; i < 64; i++) {
    u32 e = (s[i] >> 7) & 0xFFu;
    cnt += (e >= 100u && e <= 140u) ? 1 : 0;
  }
  return cnt < 48;  // 1 => fp32
}

__device__ __forceinline__ u16 ldw(const void* W, size_t idx, int isf32) {
  return isf32 ? f2b(((const float*)W)[idx]) : ((const u16*)W)[idx];
}

// ---------------------------------------------------------------------------
// Ingest: canonicalize seq (2M elems) + 6 small vectors to bf16 in ws.
// ---------------------------------------------------------------------------
__global__ __launch_bounds__(256) void ingest_kernel(
    const void* __restrict__ seq, const void* __restrict__ g1,
    const void* __restrict__ be1, const void* __restrict__ b1,
    const void* __restrict__ b2v, const void* __restrict__ g2,
    const void* __restrict__ be2, u16* __restrict__ sbuf,
    u16* __restrict__ vecs) {
  int isf32 = detect_f32(seq);
  int bx = blockIdx.x, tid = threadIdx.x;
  if (bx < 2048) {
    size_t i = (size_t)bx * 1024 + tid * 4;
    if (isf32) {
      const float* sp = (const float*)seq;
      u16 o0 = f2b(sp[i]), o1 = f2b(sp[i + 1]), o2 = f2b(sp[i + 2]), o3 = f2b(sp[i + 3]);
      uint2 ov; ov.x = (u32)o0 | ((u32)o1 << 16); ov.y = (u32)o2 | ((u32)o3 << 16);
      *(uint2*)(sbuf + i) = ov;
    } else {
      *(uint2*)(sbuf + i) = ((const uint2*)seq)[i >> 2];
    }
  } else {
    int t = bx - 2048;
    const void* src; int n;
    switch (t) {
      case 0: src = g1;  n = 256; break;
      case 1: src = be1; n = 256; break;
      case 2: src = b1;  n = 128; break;
      case 3: src = b2v; n = 256; break;
      case 4: src = g2;  n = 256; break;
      default: src = be2; n = 256; break;
    }
    if (tid < n) vecs[t * 256 + tid] = ldw(src, tid, isf32);
  }
}

// ---------------------------------------------------------------------------
// Pack weights into B-fragment-linear layout: frag f=(kt*NT+nt),
// elements (f*64+lane)*8+j ; j = consecutive k.  grid (256, 6), 256 thr.
// ---------------------------------------------------------------------------
__global__ __launch_bounds__(256) void pack_kernel(
    const void* __restrict__ Wq, const void* __restrict__ Wk,
    const void* __restrict__ Wv, const void* __restrict__ Wo,
    const void* __restrict__ W1, const void* __restrict__ W2,
    const void* __restrict__ seq,
    u16* __restrict__ pWq, u16* __restrict__ pWk, u16* __restrict__ pWv,
    u16* __restrict__ pWo, u16* __restrict__ pW1, u16* __restrict__ pW2) {
  int isf32 = detect_f32(seq);
  const void* W; u16* P; int K, N;
  switch (blockIdx.y) {
    case 0: W = Wq; P = pWq; K = 256;  N = 2048; break;
    case 1: W = Wk; P = pWk; K = 256;  N = 2048; break;
    case 2: W = Wv; P = pWv; K = 256;  N = 2048; break;
    case 3: W = Wo; P = pWo; K = 2048; N = 256;  break;
    case 4: W = W1; P = pW1; K = 256;  N = 128;  break;
    default: W = W2; P = pW2; K = 128; N = 256;  break;
  }
  int t = blockIdx.x * 256 + threadIdx.x;
  int total = (K >> 5) * (N >> 4) * 64;
  if (t >= total) return;
  int lane = t & 63, f = t >> 6;
  int NT = N >> 4;
  int kt = f / NT, nt = f - kt * NT;
  int row0 = kt * 32 + ((lane >> 4) << 3);
  int col = nt * 16 + (lane & 15);
  u16 e[8];
  #pragma unroll
  for (int j = 0; j < 8; j++) e[j] = ldw(W, (size_t)(row0 + j) * N + col, isf32);
  uint4 u;
  u.x = (u32)e[0] | ((u32)e[1] << 16);
  u.y = (u32)e[2] | ((u32)e[3] << 16);
  u.z = (u32)e[4] | ((u32)e[5] << 16);
  u.w = (u32)e[6] | ((u32)e[7] << 16);
  *(uint4*)(P + ((size_t)f * 64 + lane) * 8) = u;
}

// ---------------------------------------------------------------------------
// QKV projection for one h-chunk: X(8192x256) @ W(256, hc*256).
// Q,K -> [B,hc,L,D]; V -> transposed [B,hc,D,L].
// grid (2*hc, 64, 3), 256 threads (4 waves x 32 rows each).
// ---------------------------------------------------------------------------
__global__ __launch_bounds__(256) void qkv_kernel(
    const u16* __restrict__ X,
    const u16* __restrict__ pWq, const u16* __restrict__ pWk,
    const u16* __restrict__ pWv,
    u16* __restrict__ Qo, u16* __restrict__ Ko, u16* __restrict__ Vo,
    int ntbase, int hc) {
  __shared__ u16 blds[64 * 512];  // 8 kt x 8 nt frags = 64 KB
  const u16* Pw = (blockIdx.z == 0) ? pWq : ((blockIdx.z == 1) ? pWk : pWv);
  u16* Out = (blockIdx.z == 0) ? Qo : ((blockIdx.z == 1) ? Ko : Vo);
  int tid = threadIdx.x, lane = tid & 63, w = tid >> 6;
  int nt0 = ntbase + blockIdx.x * 8;   // global n-tile base for this block
  #pragma unroll
  for (int i = 0; i < 16; i++) {
    int u = tid + i * 256;          // 0..4095 uint4s
    int fl = u >> 6, q = u & 63;
    int kt = fl >> 3, nt = fl & 7;
    ((uint4*)blds)[u] = ((const uint4*)Pw)[(size_t)(kt * 128 + nt0 + nt) * 64 + q];
  }
  __syncthreads();
  int m0 = blockIdx.y * 128 + w * 32;
  f32x4 acc[2][8] = {};
  for (int kt = 0; kt < 8; kt++) {
    bf16x8 a0 = ldb8(X + (size_t)(m0 + (lane & 15)) * 256 + kt * 32 + (lane >> 4) * 8);
    bf16x8 a1 = ldb8(X + (size_t)(m0 + 16 + (lane & 15)) * 256 + kt * 32 + (lane >> 4) * 8);
    const u16* bp = blds + (size_t)kt * 8 * 512 + (size_t)lane * 8;
    #pragma unroll
    for (int nt = 0; nt < 8; nt++) {
      bf16x8 b = ldb8(bp + nt * 512);
      acc[0][nt] = MFMA(a0, b, acc[0][nt]);
      acc[1][nt] = MFMA(a1, b, acc[1][nt]);
    }
  }
  int isv = (blockIdx.z == 2);
  #pragma unroll
  for (int mt = 0; mt < 2; mt++) {
    int rbase = m0 + mt * 16 + (lane >> 4) * 4;
    #pragma unroll
    for (int nt = 0; nt < 8; nt++) {
      int nl = blockIdx.x * 128 + nt * 16 + (lane & 15);  // within chunk
      int hl = nl >> 8, dd = nl & 255;
      #pragma unroll
      for (int r = 0; r < 4; r++) {
        int m = rbase + r;
        int bi = m >> 11, l = m & 2047;
        u16 val = f2b(acc[mt][nt][r]);
        if (isv)  // V^T: [B,hc,D,L]
          Out[((size_t)(bi * hc + hl) * 256 + dd) * 2048 + l] = val;
        else      // Q/K: [B,hc,L,D]
          Out[((size_t)(bi * hc + hl) * 2048 + l) * 256 + dd] = val;
      }
    }
  }
}

// ---------------------------------------------------------------------------
// Flash attention per (b,hl).  grid (4*hc, 32), 256 threads.
// 64 queries/block (16/wave), 32-key steps. scale = 1/sqrt(256) = 1/16.
// K staged [key][d] (stride 264); V^T staged [d][key] (stride 36) from the
// pre-transposed global V^T — no in-loop transpose, no scalar LDS scatter.
// ---------------------------------------------------------------------------
__global__ __launch_bounds__(256, 4) void attn_kernel(
    const u16* __restrict__ Q, const u16* __restrict__ K,
    const u16* __restrict__ Vt, u16* __restrict__ O) {
  __shared__ u16 klds[32 * 264];        // 16896 B
  __shared__ u16 vlds[256 * 36];        // 18432 B
  __shared__ u16 plds[4 * 16 * 40];     //  5120 B   (total 40448 <= 40960*4/CU)
  int tid = threadIdx.x, lane = tid & 63, w = tid >> 6;
  int bh = blockIdx.x, qt = blockIdx.y;
  const u16* Qb  = Q  + (size_t)bh * 2048 * 256;
  const u16* Kb  = K  + (size_t)bh * 2048 * 256;
  const u16* Vtb = Vt + (size_t)bh * 256 * 2048;
  u16* Ob = O + (size_t)bh * 2048 * 256;
  int q0 = qt * 64 + w * 16;
  bf16x8 qf[8];
  #pragma unroll
  for (int kt = 0; kt < 8; kt++)
    qf[kt] = ldb8(Qb + (size_t)(q0 + (lane & 15)) * 256 + kt * 32 + (lane >> 4) * 8);
  f32x4 o[16] = {};
  float m_i[4] = {-1e30f, -1e30f, -1e30f, -1e30f};
  float l_i[4] = {0.f, 0.f, 0.f, 0.f};
  const float cexp = 0.0625f * 1.44269504088896f;  // scale * log2(e)
  u16* pl = plds + w * 16 * 40;

  for (int s0 = 0; s0 < 2048; s0 += 32) {
    __syncthreads();  // previous iteration's LDS reads done before overwrite
    #pragma unroll
    for (int i = 0; i < 4; i++) {
      // K-tile: 1024 16B-chunks, [key][d]
      int c = i * 256 + tid;
      int row = c >> 5, col = (c & 31) * 8;
      *(uint4*)(klds + row * 264 + col) =
          *(const uint4*)(Kb + (size_t)(s0 + row) * 256 + col);
      // V^T-tile: 1024 16B-chunks, [d][key]; 4 chunks of 8 keys per d-row
      int d = c >> 2, ck = (c & 3) * 8;
      *(uint4*)(vlds + d * 36 + ck) =
          *(const uint4*)(Vtb + (size_t)d * 2048 + s0 + ck);
    }
    __syncthreads();
    // S = Q K^T  (16 queries x 32 keys), fp32
    f32x4 s[2] = {};
    #pragma unroll
    for (int ntk = 0; ntk < 2; ntk++) {
      const u16* kp = klds + ((lane & 15) + 16 * ntk) * 264 + (lane >> 4) * 8;
      #pragma unroll
      for (int kt = 0; kt < 8; kt++) {
        bf16x8 b = ldb8(kp + kt * 32);
        s[ntk] = MFMA(qf[kt], b, s[ntk]);
      }
    }
    // online softmax (exp2 domain)
    float alpha[4];
    f32x4 p[2];
    #pragma unroll
    for (int r = 0; r < 4; r++) {
      float mx = fmaxf(s[0][r], s[1][r]);
      mx = fmaxf(mx, __shfl_xor(mx, 1));
      mx = fmaxf(mx, __shfl_xor(mx, 2));
      mx = fmaxf(mx, __shfl_xor(mx, 4));
      mx = fmaxf(mx, __shfl_xor(mx, 8));
      float mn = fmaxf(m_i[r], mx);
      alpha[r] = exp2f((m_i[r] - mn) * cexp);
      p[0][r] = exp2f((s[0][r] - mn) * cexp);
      p[1][r] = exp2f((s[1][r] - mn) * cexp);
      float ps = p[0][r] + p[1][r];
      ps += __shfl_xor(ps, 1);
      ps += __shfl_xor(ps, 2);
      ps += __shfl_xor(ps, 4);
      ps += __shfl_xor(ps, 8);
      l_i[r] = l_i[r] * alpha[r] + ps;
      m_i[r] = mn;
    }
    int need = (alpha[0] < 1.f) | (alpha[1] < 1.f) | (alpha[2] < 1.f) | (alpha[3] < 1.f);
    if (__any(need)) {
      #pragma unroll
      for (int nt = 0; nt < 16; nt++)
        #pragma unroll
        for (int r = 0; r < 4; r++) o[nt][r] *= alpha[r];
    }
    // P (C-layout) -> per-wave LDS -> A-layout (wave-private: waitcnt only)
    #pragma unroll
    for (int ntk = 0; ntk < 2; ntk++)
      #pragma unroll
      for (int r = 0; r < 4; r++)
        pl[((lane >> 4) * 4 + r) * 40 + ntk * 16 + (lane & 15)] = f2b(p[ntk][r]);
    asm volatile("s_waitcnt lgkmcnt(0)" ::: "memory");
    bf16x8 pa = ldb8(pl + (lane & 15) * 40 + (lane >> 4) * 8);
    #pragma unroll
    for (int nt = 0; nt < 16; nt++) {
      bf16x8 vb = ldb8(vlds + (size_t)(nt * 16 + (lane & 15)) * 36 + (lane >> 4) * 8);
      o[nt] = MFMA(pa, vb, o[nt]);
    }
  }
  float linv[4];
  #pragma unroll
  for (int r = 0; r < 4; r++) linv[r] = 1.0f / l_i[r];
  #pragma unroll
  for (int nt = 0; nt < 16; nt++) {
    int d = nt * 16 + (lane & 15);
    #pragma unroll
    for (int r = 0; r < 4; r++) {
      int qrow = q0 + (lane >> 4) * 4 + r;
      Ob[(size_t)qrow * 256 + d] = f2b(o[nt][r] * linv[r]);
    }
  }
}

// ---------------------------------------------------------------------------
// att_out(f32) += O_chunk @ Wo_chunk.  grid (128), 256 threads.
// ---------------------------------------------------------------------------
__global__ __launch_bounds__(256) void accum_kernel(
    const u16* __restrict__ Oc, const u16* __restrict__ pWo,
    float* __restrict__ att_out, int kt0, int hc) {
  __shared__ u16 blds[64 * 512];  // 4 kt x 16 nt frags = 64 KB
  int tid = threadIdx.x, lane = tid & 63, w = tid >> 6;
  int m0 = blockIdx.x * 64 + w * 16;
  int arow = m0 + (lane & 15);
  int bq = arow >> 11, lrow = arow & 2047;
  int ktn = hc * 8;
  f32x4 acc[16] = {};
  for (int k0 = 0; k0 < ktn; k0 += 4) {
    __syncthreads();
    #pragma unroll
    for (int i = 0; i < 16; i++) {
      int u = tid + i * 256;
      int fl = u >> 6, q = u & 63;
      int ktg = kt0 + k0 + (fl >> 4), nt = fl & 15;
      ((uint4*)blds)[u] = ((const uint4*)pWo)[(size_t)(ktg * 16 + nt) * 64 + q];
    }
    __syncthreads();
    #pragma unroll
    for (int kl = 0; kl < 4; kl++) {
      int ktl = k0 + kl;                 // local kt within chunk
      int hl = ktl >> 3;
      int d0 = (ktl & 7) * 32 + (lane >> 4) * 8;
      bf16x8 a = ldb8(Oc + ((size_t)(bq * hc + hl) * 2048 + lrow) * 256 + d0);
      const u16* bp = blds + (size_t)kl * 16 * 512 + (size_t)lane * 8;
      #pragma unroll
      for (int nt = 0; nt < 16; nt++) {
        bf16x8 b = ldb8(bp + nt * 512);
        acc[nt] = MFMA(a, b, acc[nt]);
      }
    }
  }
  int rbase = m0 + (lane >> 4) * 4;
  #pragma unroll
  for (int nt = 0; nt < 16; nt++) {
    int d = nt * 16 + (lane & 15);
    #pragma unroll
    for (int r = 0; r < 4; r++)
      att_out[(size_t)(rbase + r) * 256 + d] += acc[nt][r];
  }
}

// ---------------------------------------------------------------------------
// x = LN1(seq + att_out).  grid (2048), 256 threads; 1 wave per row.
// ---------------------------------------------------------------------------
__global__ __launch_bounds__(256) void ln1_kernel(
    const float* __restrict__ att_out, const u16* __restrict__ sbuf,
    const u16* __restrict__ vecs, u16* __restrict__ xout) {
  int tid = threadIdx.x, lane = tid & 63, w = tid >> 6;
  int row = blockIdx.x * 4 + w;
  const float* ar = att_out + (size_t)row * 256;
  f32x4 a = *(const f32x4*)(ar + lane * 4);
  uint2 sv = *(const uint2*)(sbuf + (size_t)row * 256 + lane * 4);
  float y[4];
  y[0] = a[0] + b2f((u16)(sv.x & 0xFFFF));
  y[1] = a[1] + b2f((u16)(sv.x >> 16));
  y[2] = a[2] + b2f((u16)(sv.y & 0xFFFF));
  y[3] = a[3] + b2f((u16)(sv.y >> 16));
  float sm = y[0] + y[1] + y[2] + y[3];
  sm += __shfl_xor(sm, 1);  sm += __shfl_xor(sm, 2);  sm += __shfl_xor(sm, 4);
  sm += __shfl_xor(sm, 8);  sm += __shfl_xor(sm, 16); sm += __shfl_xor(sm, 32);
  float mu = sm * (1.0f / 256.0f);
  float v = 0.f;
  #pragma unroll
  for (int j = 0; j < 4; j++) { float d = y[j] - mu; v += d * d; }
  v += __shfl_xor(v, 1);  v += __shfl_xor(v, 2);  v += __shfl_xor(v, 4);
  v += __shfl_xor(v, 8);  v += __shfl_xor(v, 16); v += __shfl_xor(v, 32);
  float rs = rsqrtf(v * (1.0f / 256.0f) + 1e-5f);
  u16 o[4];
  #pragma unroll
  for (int j = 0; j < 4; j++) {
    int d = lane * 4 + j;
    o[j] = f2b((y[j] - mu) * rs * b2f(vecs[d]) + b2f(vecs[256 + d]));
  }
  uint2 ov; ov.x = (u32)o[0] | ((u32)o[1] << 16); ov.y = (u32)o[2] | ((u32)o[3] << 16);
  *(uint2*)(xout + (size_t)row * 256 + lane * 4) = ov;
}

// ---------------------------------------------------------------------------
// FFN + LN2.  out = LN2(x + relu(x@W1+b1)@W2 + b2).  grid(128), 256 thr.
// ---------------------------------------------------------------------------
__global__ __launch_bounds__(256) void ffn_ln2_kernel(
    const u16* __restrict__ x, const u16* __restrict__ pW1,
    const u16* __restrict__ pW2, const u16* __restrict__ vecs,
    const void* __restrict__ seq, void* __restrict__ out) {
  __shared__ u16 hbuf[4 * 16 * 136];  // per-wave h [16][128], stride 136
  int isf32 = detect_f32(seq);
  int tid = threadIdx.x, lane = tid & 63, w = tid >> 6;
  int m0 = blockIdx.x * 64 + w * 16;
  int arow = m0 + (lane & 15);
  u16* hb = hbuf + w * 16 * 136;
  // phase 1: h = relu(x @ W1 + b1)
  f32x4 acc1[8] = {};
  #pragma unroll
  for (int kt = 0; kt < 8; kt++) {
    bf16x8 a = ldb8(x + (size_t)arow * 256 + kt * 32 + (lane >> 4) * 8);
    const u16* bp = pW1 + ((size_t)kt * 8 * 64 + lane) * 8;
    #pragma unroll
    for (int nt = 0; nt < 8; nt++) {
      bf16x8 b = ldb8(bp + nt * 512);
      acc1[nt] = MFMA(a, b, acc1[nt]);
    }
  }
  #pragma unroll
  for (int nt = 0; nt < 8; nt++) {
    int col = nt * 16 + (lane & 15);
    float bb = b2f(vecs[512 + col]);
    #pragma unroll
    for (int r = 0; r < 4; r++) {
      float h = fmaxf(acc1[nt][r] + bb, 0.f);
      hb[((lane >> 4) * 4 + r) * 136 + col] = f2b(h);
    }
  }
  __syncthreads();
  // phase 2: y = h @ W2
  f32x4 acc2[16] = {};
  #pragma unroll
  for (int ks = 0; ks < 4; ks++) {
    bf16x8 a = ldb8(hb + (lane & 15) * 136 + ks * 32 + (lane >> 4) * 8);
    const u16* bp = pW2 + ((size_t)ks * 16 * 64 + lane) * 8;
    #pragma unroll
    for (int nt = 0; nt < 16; nt++) {
      bf16x8 b = ldb8(bp + nt * 512);
      acc2[nt] = MFMA(a, b, acc2[nt]);
    }
  }
  int rbase = m0 + (lane >> 4) * 4;
  #pragma unroll
  for (int nt = 0; nt < 16; nt++) {
    int d = nt * 16 + (lane & 15);
    float bb = b2f(vecs[768 + d]);
    #pragma unroll
    for (int r = 0; r < 4; r++)
      acc2[nt][r] += bb + b2f(x[(size_t)(rbase + r) * 256 + d]);
  }
  float mu[4], rs[4];
  #pragma unroll
  for (int r = 0; r < 4; r++) {
    float sm = 0.f;
    #pragma unroll
    for (int nt = 0; nt < 16; nt++) sm += acc2[nt][r];
    sm += __shfl_xor(sm, 1); sm += __shfl_xor(sm, 2);
    sm += __shfl_xor(sm, 4); sm += __shfl_xor(sm, 8);
    mu[r] = sm * (1.0f / 256.0f);
    float v = 0.f;
    #pragma unroll
    for (int nt = 0; nt < 16; nt++) { float dd = acc2[nt][r] - mu[r]; v += dd * dd; }
    v += __shfl_xor(v, 1); v += __shfl_xor(v, 2);
    v += __shfl_xor(v, 4); v += __shfl_xor(v, 8);
    rs[r] = rsqrtf(v * (1.0f / 256.0f) + 1e-5f);
  }
  #pragma unroll
  for (int nt = 0; nt < 16; nt++) {
    int d = nt * 16 + (lane & 15);
    float gg = b2f(vecs[1024 + d]), bb = b2f(vecs[1280 + d]);
    #pragma unroll
    for (int r = 0; r < 4; r++) {
      float val = (acc2[nt][r] - mu[r]) * rs[r] * gg + bb;
      size_t idx = (size_t)(rbase + r) * 256 + d;
      if (isf32) ((float*)out)[idx] = val;
      else       ((u16*)out)[idx]   = f2b(val);
    }
  }
}

// ---------------------------------------------------------------------------
// Sentinel: workspace too small — write 777.0 beacon.
// ---------------------------------------------------------------------------
__global__ __launch_bounds__(256) void sentinel_kernel(void* out, int n,
                                                       const void* seq) {
  int isf32 = detect_f32(seq);
  int i = blockIdx.x * 256 + threadIdx.x;
  if (i < n) {
    if (isf32) ((float*)out)[i] = 777.0f;
    else       ((u16*)out)[i]   = 0x4442;  // bf16(777.0)
  }
}

// ---------------------------------------------------------------------------
extern "C" void kernel_launch(void* const* d_in, const int* in_sizes, int n_in,
                              void* d_out, int out_size, void* d_ws, size_t ws_size,
                              hipStream_t stream) {
  (void)in_sizes; (void)n_in;
  const void* seq  = d_in[0];
  const void* Wq   = d_in[1];
  const void* Wk   = d_in[2];
  const void* Wv   = d_in[3];
  const void* Wo   = d_in[4];
  const void* g1   = d_in[5];
  const void* be1  = d_in[6];
  const void* W1   = d_in[7];
  const void* b1   = d_in[8];
  const void* W2   = d_in[9];
  const void* b2   = d_in[10];
  const void* g2   = d_in[11];
  const void* be2  = d_in[12];

  // ws layout (u16 element offsets)
  size_t o = 0;
  u16* ws = (u16*)d_ws;
  u16* pWq = ws + o; o += 524288;
  u16* pWk = ws + o; o += 524288;
  u16* pWv = ws + o; o += 524288;
  u16* pWo = ws + o; o += 524288;
  u16* pW1 = ws + o; o += 32768;
  u16* pW2 = ws + o; o += 32768;
  float* att = (float*)(ws + o); o += 4194304;   // 2M f32
  u16* xb   = ws + o; o += 2097152;
  u16* sbuf = ws + o; o += 2097152;
  u16* vecs = ws + o; o += 2048;
  size_t fixed_elems = o;

  // pick hc: largest in {8,4,2,1} s.t. fixed + 4*hc*2097152 elems fit
  int hc = 0;
  for (int c = 8; c >= 1; c >>= 1) {
    size_t need = (fixed_elems + (size_t)4 * c * 2097152) * 2;
    if (need <= ws_size) { hc = c; break; }
  }
  if (hc == 0) {
    sentinel_kernel<<<dim3((out_size + 255) / 256), 256, 0, stream>>>(
        d_out, out_size, seq);
    return;
  }
  u16* Qc = ws + o; o += (size_t)hc * 2097152;
  u16* Kc = ws + o; o += (size_t)hc * 2097152;
  u16* Vc = ws + o; o += (size_t)hc * 2097152;   // holds V^T [B,hc,D,L]
  u16* Oc = ws + o;

  hipMemsetAsync(att, 0, 2097152 * sizeof(float), stream);
  ingest_kernel<<<dim3(2054), 256, 0, stream>>>(seq, g1, be1, b1, b2, g2, be2,
                                                sbuf, vecs);
  pack_kernel<<<dim3(256, 6), 256, 0, stream>>>(Wq, Wk, Wv, Wo, W1, W2, seq,
                                                pWq, pWk, pWv, pWo, pW1, pW2);
  int nchunks = 8 / hc;
  for (int c = 0; c < nchunks; c++) {
    qkv_kernel<<<dim3(2 * hc, 64, 3), 256, 0, stream>>>(
        sbuf, pWq, pWk, pWv, Qc, Kc, Vc, c * hc * 16, hc);
    attn_kernel<<<dim3(4 * hc, 32), 256, 0, stream>>>(Qc, Kc, Vc, Oc);
    accum_kernel<<<dim3(128), 256, 0, stream>>>(Oc, pWo, att, c * hc * 8, hc);
  }
  ln1_kernel<<<dim3(2048), 256, 0, stream>>>(att, sbuf, vecs, xb);
  ffn_ln2_kernel<<<dim3(128), 256, 0, stream>>>(xb, pW1, pW2, vecs, seq,
                                                (void*)d_out);
}